// Round 23
// baseline (289.351 us; speedup 1.0000x reference)
//
#include <hip/hip_runtime.h>
#include <hip/hip_fp16.h>

// GCN 2-layer. N=250000, E=4000000, 18 -> 16 -> 1.
// R16: 5-dispatch restructure (observability + dead-kernel elimination).
// R15 (246.7us) left ~190us across 6 sub-58us dispatches that the top-5
// profile (all agg1 replicates) cannot show. Changes:
//  - bhist/bscan DELETED: sortchunk bin-sorts each 8192-edge chunk in LDS
//    and writes it to the chunk's own pairs region (base+i, fully coalesced)
//    + per-(chunk,bin) offsets pofs. No global histogram/scan/cursors.
//  - csr: bin b gathers its 489 chunk-segments via pofs (thread t streams
//    chunk t's ~17-edge segment), reserves its EXACT csr_src region from a
//    global bump allocator (1 atomicAdd/block), then count/scan/place +
//    fused h1. rowp is per-bin [489][513] (sentinel per bin).
//  - dis array DELETED: agg1/agg2 compute d = rsqrt(deg+1) from rowp.
// agg1 FROZEN (R11 form, request-path bound 2.6TB/s, 58us).
//
// out[d] = dis[d] * (sum_{s->d} hs[s] + hs[d]) + bias, hs pre-scaled by dis.

#define NB_BITS 8
#define BN (1 << NB_BITS)       // 256 nodes per agg bucket (agg1 grid)
#define SB_BITS 9
#define SBN (1 << SB_BITS)      // 512 nodes per sort bin
#define NSB 512                 // bins indexed by thread in sortchunk
#define BIN_TPB 512
#define BIN_CHUNK 8192
#define AGG_TPB 512

// exclusive scan of v over 512 threads: wave shfl scan + 8-partial combine.
// 2 barriers. warpsums must be LDS int[8]; afterwards warpsums[7] == total.
__device__ __forceinline__ int exscan512(int v, int* warpsums, int t) {
    int lane = t & 63, w = t >> 6;
    int x = v;
#pragma unroll
    for (int off = 1; off < 64; off <<= 1) {
        int y = __shfl_up(x, off);
        if (lane >= off) x += y;
    }
    if (lane == 63) warpsums[w] = x;
    __syncthreads();
    if (w == 0) {
        int s = (lane < 8) ? warpsums[lane] : 0;
#pragma unroll
        for (int off = 1; off < 8; off <<= 1) {
            int y = __shfl_up(s, off);
            if (lane >= off) s += y;
        }
        if (lane < 8) warpsums[lane] = s;
    }
    __syncthreads();
    int base = (w > 0) ? warpsums[w - 1] : 0;
    return base + x - v;  // exclusive
}

// bin-sort one 8192-edge chunk in LDS; write back to the chunk's own pairs
// region (coalesced) + per-(chunk,bin) offsets. pairs = (src<<9 | dst&511).
__global__ void sortchunk_kernel(const int* __restrict__ src, const int* __restrict__ dst,
                                 int* __restrict__ pairs, int* __restrict__ pofs, int E) {
    __shared__ int cnt[NSB];
    __shared__ int lcur[NSB];
    __shared__ int warpsums[8];
    __shared__ int lbuf[BIN_CHUNK];            // 32KB
    int t = threadIdx.x, c = blockIdx.x;
    int base = c * BIN_CHUNK;
    int end = min(base + BIN_CHUNK, E);
    int full = (end - base == BIN_CHUNK);
    cnt[t] = 0;
    __syncthreads();
    if (full) {
        const int4* d4 = (const int4*)(dst + base);
#pragma unroll
        for (int i = 0; i < BIN_CHUNK / (BIN_TPB * 4); i++) {
            int4 v = d4[t + i * BIN_TPB];
            atomicAdd(&cnt[v.x >> SB_BITS], 1);
            atomicAdd(&cnt[v.y >> SB_BITS], 1);
            atomicAdd(&cnt[v.z >> SB_BITS], 1);
            atomicAdd(&cnt[v.w >> SB_BITS], 1);
        }
    } else {
        for (int e = base + t; e < end; e += BIN_TPB)
            atomicAdd(&cnt[dst[e] >> SB_BITS], 1);
    }
    __syncthreads();
    int v = cnt[t];
    int excl = exscan512(v, warpsums, t);   // 2 barriers
    lcur[t] = excl;
    pofs[(size_t)c * (NSB + 1) + t] = excl;
    if (t == 0) pofs[(size_t)c * (NSB + 1) + NSB] = end - base;
    __syncthreads();
    // scatter into LDS in bin-sorted order
    if (full) {
        const int4* s4 = (const int4*)(src + base);
        const int4* d4 = (const int4*)(dst + base);
#pragma unroll
        for (int i = 0; i < BIN_CHUNK / (BIN_TPB * 4); i++) {
            int4 dv = d4[t + i * BIN_TPB];
            int4 sv = s4[t + i * BIN_TPB];
            int b0 = dv.x >> SB_BITS, p0 = atomicAdd(&lcur[b0], 1);
            lbuf[p0] = (sv.x << SB_BITS) | (dv.x & (SBN - 1));
            int b1 = dv.y >> SB_BITS, p1 = atomicAdd(&lcur[b1], 1);
            lbuf[p1] = (sv.y << SB_BITS) | (dv.y & (SBN - 1));
            int b2 = dv.z >> SB_BITS, p2 = atomicAdd(&lcur[b2], 1);
            lbuf[p2] = (sv.z << SB_BITS) | (dv.z & (SBN - 1));
            int b3 = dv.w >> SB_BITS, p3 = atomicAdd(&lcur[b3], 1);
            lbuf[p3] = (sv.w << SB_BITS) | (dv.w & (SBN - 1));
        }
    } else {
        for (int e = base + t; e < end; e += BIN_TPB) {
            int d = dst[e], s = src[e];
            int b = d >> SB_BITS;
            int pos = atomicAdd(&lcur[b], 1);
            lbuf[pos] = (s << SB_BITS) | (d & (SBN - 1));
        }
    }
    __syncthreads();
    // coalesced write-back to this chunk's own region
    int n = end - base;
#pragma unroll 4
    for (int i = t; i < n; i += BIN_TPB) pairs[base + i] = lbuf[i];
}

// per-bin CSR build + fused h1. Bin b gathers its segment from each chunk
// (thread t owns chunk t), bump-allocates its exact csr_src region, then
// count/scan/place. Tail: thread t computes node nbase+t's hs1 row.
__global__ void csr_kernel(const int* __restrict__ pairs, const int* __restrict__ pofs,
                           int* __restrict__ alloc, int* __restrict__ rowp,
                           int* __restrict__ csr_src, const float* __restrict__ x,
                           const float* __restrict__ W1, __half* __restrict__ hs1h,
                           int N, int NCHUNK) {
    __shared__ int cnt[SBN];
    __shared__ int warpsums[8];
    __shared__ float w[18 * 16];
    __shared__ int regbase_s;
    int b = blockIdx.x, t = threadIdx.x;   // TPB == SBN == 512
    cnt[t] = 0;
    if (t < 18 * 16) w[t] = W1[t];
    int seg0 = 0, seg1 = 0;
    if (t < NCHUNK) {
        int s = pofs[(size_t)t * (NSB + 1) + b];
        int e = pofs[(size_t)t * (NSB + 1) + b + 1];
        seg0 = t * BIN_CHUNK + s;
        seg1 = t * BIN_CHUNK + e;
    }
    __syncthreads();
    // count phase: each thread streams its chunk's segment
    for (int i = seg0; i < seg1; ++i)
        atomicAdd(&cnt[pairs[i] & (SBN - 1)], 1);
    __syncthreads();
    int v = cnt[t];
    int excl = exscan512(v, warpsums, t);   // 2 barriers; warpsums[7]=total
    if (t == 0) regbase_s = atomicAdd(alloc, warpsums[7]);
    __syncthreads();
    int regbase = regbase_s;
    int nbase = b << SB_BITS;
    int start = regbase + excl;
    rowp[(size_t)b * (SBN + 1) + t] = start;
    if (t == 0) rowp[(size_t)b * (SBN + 1) + SBN] = regbase + warpsums[7];
    int n = nbase + t;
    float dv = rsqrtf((float)v + 1.0f);
    cnt[t] = start;                // reuse as placement cursor (post-barrier)
    __syncthreads();
    // place phase: stream segments again, scatter into csr_src region
    for (int i = seg0; i < seg1; ++i) {
        int pv = pairs[i];
        int pos = atomicAdd(&cnt[pv & (SBN - 1)], 1);
        csr_src[pos] = pv >> SB_BITS;
    }
    // fused h1 tail: registers + stable w[] only
    if (n < N) {
        const float2* x2 = (const float2*)(x + (size_t)n * 18);
        float xv[18];
#pragma unroll
        for (int k = 0; k < 9; k++) {
            float2 vv = x2[k];
            xv[2 * k] = vv.x;
            xv[2 * k + 1] = vv.y;
        }
        float acc[16];
#pragma unroll
        for (int f = 0; f < 16; f++) acc[f] = 0.0f;
#pragma unroll
        for (int k = 0; k < 18; k++) {
            float xk = xv[k];
#pragma unroll
            for (int f = 0; f < 16; f++) acc[f] = fmaf(xk, w[k * 16 + f], acc[f]);
        }
        unsigned int u[8];
#pragma unroll
        for (int q = 0; q < 8; q++) {
            unsigned int lo = __half_as_ushort(__float2half_rn(acc[2 * q] * dv));
            unsigned int hi = __half_as_ushort(__float2half_rn(acc[2 * q + 1] * dv));
            u[q] = lo | (hi << 16);
        }
        uint4* outp = (uint4*)(hs1h + (size_t)n * 16);
        outp[0] = make_uint4(u[0], u[1], u[2], u[3]);
        outp[1] = make_uint4(u[4], u[5], u[6], u[7]);
    }
}

// layer-1: CSR, one node per 16-lane group, REGISTER accumulation (frozen
// R11 form). d recomputed from rowp (deg = r1-r0); rowp is per-bin [513].
__global__ void agg1_kernel(const int* __restrict__ csr_src, const int* __restrict__ rowp,
                            const __half* __restrict__ hs1h, const float* __restrict__ b1,
                            const float* __restrict__ W2, float* __restrict__ hs2, int N) {
    int b = blockIdx.x, t = threadIdx.x;
    int f = t & 15;
    int g = t >> 4;                 // 0..31 groups
    float bbf = b1[f], wwf = W2[f];
    int nbase = b << NB_BITS;
    for (int nl = g; nl < BN; nl += AGG_TPB / 16) {
        int n = nbase + nl;
        if (n >= N) continue;
        int bb = n >> SB_BITS, ii = n & (SBN - 1);
        int r0 = rowp[(size_t)bb * (SBN + 1) + ii];
        int r1 = rowp[(size_t)bb * (SBN + 1) + ii + 1];
        float a = 0.f;
#pragma unroll 4
        for (int r = r0; r < r1; ++r) {
            int s = csr_src[r];     // group-uniform broadcast load
            a += __half2float(hs1h[(size_t)s * 16 + f]);
        }
        float d = rsqrtf((float)(r1 - r0) + 1.0f);
        float self = __half2float(hs1h[(size_t)n * 16 + f]);
        float p = fmaxf(d * (a + self) + bbf, 0.f) * wwf;
        p += __shfl_xor(p, 1);
        p += __shfl_xor(p, 2);
        p += __shfl_xor(p, 4);
        p += __shfl_xor(p, 8);
        if (f == 0) hs2[n] = p * d;
    }
}

// layer-2: CSR, one node per 16-lane group; lanes split the run, shfl reduce.
__global__ void agg2_kernel(const int* __restrict__ csr_src, const int* __restrict__ rowp,
                            const float* __restrict__ hs2, const float* __restrict__ b2,
                            float* __restrict__ out, int N) {
    int b = blockIdx.x, t = threadIdx.x;
    int l = t & 15;
    int g = t >> 4;
    int nbase = b << NB_BITS;
    float bb = b2[0];
    for (int nl = g; nl < BN; nl += AGG_TPB / 16) {
        int n = nbase + nl;
        if (n >= N) continue;
        int bbn = n >> SB_BITS, ii = n & (SBN - 1);
        int r0 = rowp[(size_t)bbn * (SBN + 1) + ii];
        int r1 = rowp[(size_t)bbn * (SBN + 1) + ii + 1];
        float a = 0.f;
        for (int r = r0 + l; r < r1; r += 16) a += hs2[csr_src[r]];
        a += __shfl_xor(a, 1);
        a += __shfl_xor(a, 2);
        a += __shfl_xor(a, 4);
        a += __shfl_xor(a, 8);
        if (l == 0) {
            float d = rsqrtf((float)(r1 - r0) + 1.0f);
            out[n] = d * (a + hs2[n]) + bb;
        }
    }
}

extern "C" void kernel_launch(void* const* d_in, const int* in_sizes, int n_in,
                              void* d_out, int out_size, void* d_ws, size_t ws_size,
                              hipStream_t stream) {
    const float* x = (const float*)d_in[0];
    const int* edge_index = (const int*)d_in[1];
    const float* W1 = (const float*)d_in[2];
    const float* b1 = (const float*)d_in[3];
    const float* W2 = (const float*)d_in[4];
    const float* b2 = (const float*)d_in[5];
    float* out = (float*)d_out;

    const int N = in_sizes[0] / 18;
    const int E = in_sizes[1] / 2;
    const int* src = edge_index;
    const int* dst = edge_index + E;
    const int NABUCKET = (N + BN - 1) / BN;          // 977 agg blocks
    const int NSBUCKET = (N + SBN - 1) / SBN;        // 489 bins
    const int NCHUNK = (E + BIN_CHUNK - 1) / BIN_CHUNK;  // 489 chunks

    // ws layout (4B words): pairs[NCHUNK*8192], csr_src[E],
    // hs1h(16 fp16/node = 8N words), hs2[N], rowp[NSBUCKET*513],
    // pofs[NCHUNK*513], alloc[1]  ~= 43.1 MB
    int* ws = (int*)d_ws;
    int* pairs = ws;
    int* csr_src = pairs + (size_t)NCHUNK * BIN_CHUNK;
    __half* hs1h = (__half*)(csr_src + (size_t)E);
    float* hs2 = (float*)((int*)(csr_src + (size_t)E) + 8 * (size_t)N);
    int* rowp = (int*)(hs2 + N);
    int* pofs = rowp + (size_t)NSBUCKET * (SBN + 1);
    int* alloc = pofs + (size_t)NCHUNK * (NSB + 1);

    hipMemsetAsync(alloc, 0, sizeof(int), stream);

    sortchunk_kernel<<<NCHUNK, BIN_TPB, 0, stream>>>(src, dst, pairs, pofs, E);
    csr_kernel<<<NSBUCKET, SBN, 0, stream>>>(pairs, pofs, alloc, rowp, csr_src,
                                             x, W1, hs1h, N, NCHUNK);
    agg1_kernel<<<NABUCKET, AGG_TPB, 0, stream>>>(csr_src, rowp, hs1h, b1, W2, hs2, N);
    agg2_kernel<<<NABUCKET, AGG_TPB, 0, stream>>>(csr_src, rowp, hs2, b2, out, N);
}